// Round 2
// baseline (567.109 us; speedup 1.0000x reference)
//
#include <hip/hip_runtime.h>
#include <stdint.h>
#include <math.h>

typedef float  f32x4  __attribute__((ext_vector_type(4)));
typedef __bf16 bf16x8 __attribute__((ext_vector_type(8)));
typedef __bf16 bf16x4 __attribute__((ext_vector_type(4)));

#define LOG2E 1.4426950408889634f

// async global->LDS, 16B per lane. LDS side must be wave-uniform base + lane*16.
__device__ __forceinline__ void gl_lds16(const void* g, void* l) {
  __builtin_amdgcn_global_load_lds(
      (__attribute__((address_space(1))) void*)(uintptr_t)g,
      (__attribute__((address_space(3))) void*)l, 16, 0, 0);
}

// ---------------- cast fp32 -> bf16, x4 vectorized ----------------
__global__ __launch_bounds__(256) void k_cast(const float* __restrict__ in,
                                              __bf16* __restrict__ out, int n4) {
  int i = blockIdx.x * 256 + threadIdx.x;
  if (i >= n4) return;
  f32x4 v = ((const f32x4*)in)[i];
  ((bf16x4*)out)[i] = __builtin_convertvector(v, bf16x4);
}

// ---------------- transpose + cast: in [K][N] fp32 -> out [N][K] bf16 ----------------
__global__ __launch_bounds__(256) void k_transpose(const float* __restrict__ in,
                                                   __bf16* __restrict__ out,
                                                   int K, int N) {
  __shared__ float tile[32][33];
  int n0 = blockIdx.x * 32, k0 = blockIdx.y * 32;
  int tx = threadIdx.x & 31, ty = threadIdx.x >> 5;
#pragma unroll
  for (int i = 0; i < 32; i += 8)
    tile[ty + i][tx] = in[(size_t)(k0 + ty + i) * N + n0 + tx];
  __syncthreads();
#pragma unroll
  for (int i = 0; i < 32; i += 8)
    out[(size_t)(n0 + ty + i) * K + k0 + tx] = (__bf16)tile[tx][ty + i];
}

// ---------------- QKV GEMM: A[4096][2048] bf16 x Bt[6144][2048] bf16 ----------------
// m97 structure: 128x128 tile, BK=32, global_load_lds width 16, 2x2 waves, 4x4 acc.
__global__ __launch_bounds__(256) void k_gemm_qkv(
    const __bf16* __restrict__ A, const __bf16* __restrict__ Bt,
    const float* __restrict__ bias,
    __bf16* __restrict__ Qo, __bf16* __restrict__ Ko, __bf16* __restrict__ Vo) {
  __shared__ __bf16 sA[128 * 32];
  __shared__ __bf16 sB[128 * 32];
  const int K = 2048;
  int t = threadIdx.x;
  int m0 = blockIdx.y << 7, n0 = blockIdx.x << 7;
  int wave = t >> 6, lane = t & 63;
  int wr = wave >> 1, wc = wave & 1;
  int quad = lane >> 4, l16 = lane & 15;

  f32x4 acc[4][4] = {};

  const char* gA = (const char*)(A + (size_t)m0 * K);
  const char* gB = (const char*)(Bt + (size_t)n0 * K);
  int s0 = t, s1 = t + 256;
  int ar0 = s0 >> 2, ac0 = s0 & 3;
  int ar1 = s1 >> 2, ac1 = s1 & 3;

  for (int k0 = 0; k0 < K; k0 += 32) {
    gl_lds16(gA + (size_t)ar0 * 4096 + k0 * 2 + ac0 * 16, (char*)sA + s0 * 16);
    gl_lds16(gA + (size_t)ar1 * 4096 + k0 * 2 + ac1 * 16, (char*)sA + s1 * 16);
    gl_lds16(gB + (size_t)ar0 * 4096 + k0 * 2 + ac0 * 16, (char*)sB + s0 * 16);
    gl_lds16(gB + (size_t)ar1 * 4096 + k0 * 2 + ac1 * 16, (char*)sB + s1 * 16);
    asm volatile("s_waitcnt vmcnt(0)" ::: "memory");
    __syncthreads();

    bf16x8 af[4], bfr[4];
#pragma unroll
    for (int mt = 0; mt < 4; ++mt)
      af[mt] = *(const bf16x8*)(sA + (wr * 64 + mt * 16 + l16) * 32 + quad * 8);
#pragma unroll
    for (int nt = 0; nt < 4; ++nt)
      bfr[nt] = *(const bf16x8*)(sB + (wc * 64 + nt * 16 + l16) * 32 + quad * 8);
#pragma unroll
    for (int mt = 0; mt < 4; ++mt)
#pragma unroll
      for (int nt = 0; nt < 4; ++nt)
        acc[mt][nt] = __builtin_amdgcn_mfma_f32_16x16x32_bf16(af[mt], bfr[nt], acc[mt][nt], 0, 0, 0);
    __syncthreads();
  }

  // epilogue: scatter into Q/K/V [b*16+h][s][128] bf16 with bias.
#pragma unroll
  for (int mt = 0; mt < 4; ++mt) {
    int m = m0 + wr * 64 + mt * 16 + quad * 4;
#pragma unroll
    for (int nt = 0; nt < 4; ++nt) {
      int n = n0 + wc * 64 + nt * 16 + l16;
      int h = n / 384;
      int rem = n - h * 384;
      int which = rem >> 7;
      int d = rem & 127;
      __bf16* dst = (which == 0) ? Qo : (which == 1) ? Ko : Vo;
      float bz = bias[n];
#pragma unroll
      for (int r = 0; r < 4; ++r) {
        int mm = m + r;
        int b = mm >> 11, s = mm & 2047;
        dst[(((size_t)(b * 16 + h) * 2048 + s) << 7) + d] = (__bf16)(acc[mt][nt][r] + bz);
      }
    }
  }
}

// ---------------- Out-proj GEMM: attn[4096][2048] bf16 x Bt[2048][2048] bf16 -> f32 ----------------
__global__ __launch_bounds__(256) void k_gemm_out(
    const __bf16* __restrict__ A, const __bf16* __restrict__ Bt,
    const float* __restrict__ bias, float* __restrict__ Out) {
  __shared__ __bf16 sA[128 * 32];
  __shared__ __bf16 sB[128 * 32];
  const int K = 2048;
  int t = threadIdx.x;
  int m0 = blockIdx.y << 7, n0 = blockIdx.x << 7;
  int wave = t >> 6, lane = t & 63;
  int wr = wave >> 1, wc = wave & 1;
  int quad = lane >> 4, l16 = lane & 15;

  f32x4 acc[4][4] = {};

  const char* gA = (const char*)(A + (size_t)m0 * K);
  const char* gB = (const char*)(Bt + (size_t)n0 * K);
  int s0 = t, s1 = t + 256;
  int ar0 = s0 >> 2, ac0 = s0 & 3;
  int ar1 = s1 >> 2, ac1 = s1 & 3;

  for (int k0 = 0; k0 < K; k0 += 32) {
    gl_lds16(gA + (size_t)ar0 * 4096 + k0 * 2 + ac0 * 16, (char*)sA + s0 * 16);
    gl_lds16(gA + (size_t)ar1 * 4096 + k0 * 2 + ac1 * 16, (char*)sA + s1 * 16);
    gl_lds16(gB + (size_t)ar0 * 4096 + k0 * 2 + ac0 * 16, (char*)sB + s0 * 16);
    gl_lds16(gB + (size_t)ar1 * 4096 + k0 * 2 + ac1 * 16, (char*)sB + s1 * 16);
    asm volatile("s_waitcnt vmcnt(0)" ::: "memory");
    __syncthreads();

    bf16x8 af[4], bfr[4];
#pragma unroll
    for (int mt = 0; mt < 4; ++mt)
      af[mt] = *(const bf16x8*)(sA + (wr * 64 + mt * 16 + l16) * 32 + quad * 8);
#pragma unroll
    for (int nt = 0; nt < 4; ++nt)
      bfr[nt] = *(const bf16x8*)(sB + (wc * 64 + nt * 16 + l16) * 32 + quad * 8);
#pragma unroll
    for (int mt = 0; mt < 4; ++mt)
#pragma unroll
      for (int nt = 0; nt < 4; ++nt)
        acc[mt][nt] = __builtin_amdgcn_mfma_f32_16x16x32_bf16(af[mt], bfr[nt], acc[mt][nt], 0, 0, 0);
    __syncthreads();
  }

#pragma unroll
  for (int mt = 0; mt < 4; ++mt) {
    int m = m0 + wr * 64 + mt * 16 + quad * 4;
#pragma unroll
    for (int nt = 0; nt < 4; ++nt) {
      int n = n0 + wc * 64 + nt * 16 + l16;
      float bz = bias[n];
#pragma unroll
      for (int r = 0; r < 4; ++r)
        Out[(size_t)(m + r) * 2048 + n] = acc[mt][nt][r] + bz;
    }
  }
}

// ---------------- RoPE on Q and K, dims 0..31, in place ----------------
__global__ __launch_bounds__(256) void k_rope(__bf16* __restrict__ Q,
                                              __bf16* __restrict__ Kb) {
  int idx = blockIdx.x * 256 + threadIdx.x;  // [0, 32*2048*16)
  int i = idx & 15;
  int s = (idx >> 4) & 2047;
  size_t base = (size_t)(idx >> 4) * 128;
  // inv_freq[i] = 10000^(-i/16) = 2^(-i * log2(10000)/16)
  float ang = (float)s * exp2f(-(float)i * 0.83048202372184058f);
  float sn, cs;
  sincosf(ang, &sn, &cs);
  float x1, x2;
  x1 = (float)Q[base + i]; x2 = (float)Q[base + i + 16];
  Q[base + i]      = (__bf16)(x1 * cs - x2 * sn);
  Q[base + i + 16] = (__bf16)(x2 * cs + x1 * sn);
  x1 = (float)Kb[base + i]; x2 = (float)Kb[base + i + 16];
  Kb[base + i]      = (__bf16)(x1 * cs - x2 * sn);
  Kb[base + i + 16] = (__bf16)(x2 * cs + x1 * sn);
}

// ---------------- causal flash attention ----------------
// grid (qt=32, bh=32); block 256 = 4 waves; each wave owns 16 q rows, D=128.
// sK padded stride 136 (2-way max on B-frag reads), sV transposed stride 72,
// sP per-wave stride 72 (P C-layout -> A-layout round trip, m120 pattern).
__global__ __launch_bounds__(256) void k_attn(const __bf16* __restrict__ Qb,
                                              const __bf16* __restrict__ Kb,
                                              const __bf16* __restrict__ Vb,
                                              __bf16* __restrict__ Ob) {
  __shared__ __bf16 sK[64 * 136];
  __shared__ __bf16 sV[128 * 72];
  __shared__ __bf16 sP[4 * 16 * 72];
  int t = threadIdx.x, w = t >> 6, lane = t & 63;
  int quad = lane >> 4, l16 = lane & 15;
  int qt = blockIdx.x, bh = blockIdx.y;
  int q0 = qt * 64;
  size_t base = (size_t)bh * (2048 * 128);

  bf16x8 aq[4];
  {
    const __bf16* qp = Qb + base + (size_t)(q0 + w * 16 + l16) * 128 + quad * 8;
#pragma unroll
    for (int kc = 0; kc < 4; ++kc) aq[kc] = *(const bf16x8*)(qp + kc * 32);
  }

  f32x4 o[8] = {};
  float mrow[4], lrow[4], alpha[4];
#pragma unroll
  for (int r = 0; r < 4; ++r) { mrow[r] = -INFINITY; lrow[r] = 0.f; }

  __bf16* sp = sP + w * (16 * 72);

  for (int kt = 0; kt <= qt; ++kt) {
    int kv0 = kt * 64;
    __syncthreads();  // protect LDS vs previous iteration's reads
    {  // stage K tile [64][128] -> sK stride 136; 4 threads/row x 32 bf16 each
      int row = t >> 2, c = t & 3;
      const __bf16* g = Kb + base + (size_t)(kv0 + row) * 128 + c * 32;
#pragma unroll
      for (int i = 0; i < 4; ++i)
        *(bf16x8*)(sK + row * 136 + c * 32 + i * 8) = *(const bf16x8*)(g + i * 8);
    }
    {  // stage V tile transposed -> sV [d][kv] stride 72
      int kv = t & 63, d0 = (t >> 6) * 32;
      const __bf16* g = Vb + base + (size_t)(kv0 + kv) * 128 + d0;
#pragma unroll
      for (int i = 0; i < 4; ++i) {
        bf16x8 v = *(const bf16x8*)(g + i * 8);
#pragma unroll
        for (int j = 0; j < 8; ++j) sV[(d0 + i * 8 + j) * 72 + kv] = v[j];
      }
    }
    __syncthreads();

    // S = Q K^T * scale  (wave: 16 q-rows x 64 kv-cols)
    float sv[4][4];
#pragma unroll
    for (int nt = 0; nt < 4; ++nt) {
      f32x4 z = {};
#pragma unroll
      for (int kc = 0; kc < 4; ++kc) {
        bf16x8 bk = *(const bf16x8*)(sK + (nt * 16 + l16) * 136 + kc * 32 + quad * 8);
        z = __builtin_amdgcn_mfma_f32_16x16x32_bf16(aq[kc], bk, z, 0, 0, 0);
      }
#pragma unroll
      for (int r = 0; r < 4; ++r) sv[nt][r] = z[r] * 0.08838834764831845f;
    }
    if (kt == qt) {  // diagonal tile: causal mask (matches reference's -1e9)
#pragma unroll
      for (int nt = 0; nt < 4; ++nt) {
        int col = kv0 + nt * 16 + l16;
#pragma unroll
        for (int r = 0; r < 4; ++r) {
          int row = q0 + w * 16 + quad * 4 + r;
          if (col > row) sv[nt][r] = -1e9f;
        }
      }
    }
    // online softmax; row r of this quad = q0 + w*16 + quad*4 + r
#pragma unroll
    for (int r = 0; r < 4; ++r) {
      float mx = fmaxf(fmaxf(sv[0][r], sv[1][r]), fmaxf(sv[2][r], sv[3][r]));
#pragma unroll
      for (int off = 1; off < 16; off <<= 1) mx = fmaxf(mx, __shfl_xor(mx, off, 64));
      float mnew = fmaxf(mrow[r], mx);
      alpha[r] = exp2f((mrow[r] - mnew) * LOG2E);
      mrow[r] = mnew;
      float rs = 0.f;
#pragma unroll
      for (int nt = 0; nt < 4; ++nt) {
        float p = exp2f((sv[nt][r] - mnew) * LOG2E);
        sv[nt][r] = p;
        rs += p;
      }
#pragma unroll
      for (int off = 1; off < 16; off <<= 1) rs += __shfl_xor(rs, off, 64);
      lrow[r] = lrow[r] * alpha[r] + rs;
    }
    // P (C-layout) -> LDS -> A-layout
#pragma unroll
    for (int nt = 0; nt < 4; ++nt)
#pragma unroll
      for (int r = 0; r < 4; ++r)
        sp[(quad * 4 + r) * 72 + nt * 16 + l16] = (__bf16)sv[nt][r];
#pragma unroll
    for (int nt = 0; nt < 8; ++nt)
#pragma unroll
      for (int r = 0; r < 4; ++r) o[nt][r] *= alpha[r];
    asm volatile("s_waitcnt lgkmcnt(0)" ::: "memory");  // P writes visible (wave-private region)
    // O += P V
#pragma unroll
    for (int kc = 0; kc < 2; ++kc) {
      bf16x8 ap = *(const bf16x8*)(sp + l16 * 72 + kc * 32 + quad * 8);
#pragma unroll
      for (int nt = 0; nt < 8; ++nt) {
        bf16x8 bv = *(const bf16x8*)(sV + (nt * 16 + l16) * 72 + kc * 32 + quad * 8);
        o[nt] = __builtin_amdgcn_mfma_f32_16x16x32_bf16(ap, bv, o[nt], 0, 0, 0);
      }
    }
  }

  // epilogue: O/l -> attn buffer [b][s][h][d] bf16
  int b = bh >> 4, h = bh & 15;
#pragma unroll
  for (int r = 0; r < 4; ++r) {
    float inv = 1.f / lrow[r];
    int srow = q0 + w * 16 + quad * 4 + r;
    __bf16* op = Ob + ((size_t)((b * 2048 + srow) * 16 + h)) * 128;
#pragma unroll
    for (int nt = 0; nt < 8; ++nt)
      op[nt * 16 + l16] = (__bf16)(o[nt][r] * inv);
  }
}

extern "C" void kernel_launch(void* const* d_in, const int* in_sizes, int n_in,
                              void* d_out, int out_size, void* d_ws, size_t ws_size,
                              hipStream_t stream) {
  const float* hs   = (const float*)d_in[0];
  // d_in[1] = attention_mask: causal tril, baked into k_attn.
  const float* wqkv = (const float*)d_in[2];
  const float* bqkv = (const float*)d_in[3];
  const float* wout = (const float*)d_in[4];
  const float* bout = (const float*)d_in[5];
  float* out = (float*)d_out;

  char* ws = (char*)d_ws;
  __bf16* hsb   = (__bf16*)(ws);                // 16,777,216 B  [4096][2048]
  __bf16* attnb = (__bf16*)(ws);                // reuses hsb (dead after QKV GEMM)
  __bf16* wqkvT = (__bf16*)(ws + 16777216);     // 25,165,824 B  [6144][2048]
  __bf16* woutT = (__bf16*)(ws + 41943040);     //  8,388,608 B  [2048][2048]
  __bf16* Qb    = (__bf16*)(ws + 50331648);     // 16,777,216 B  [32][2048][128]
  __bf16* Kb    = (__bf16*)(ws + 67108864);     // 16,777,216 B
  __bf16* Vb    = (__bf16*)(ws + 83886080);     // 16,777,216 B
  // total ws use: 100,663,296 B

  k_cast<<<8192, 256, 0, stream>>>(hs, hsb, 2097152);
  k_transpose<<<dim3(192, 64), 256, 0, stream>>>(wqkv, wqkvT, 2048, 6144);
  k_transpose<<<dim3(64, 64), 256, 0, stream>>>(wout, woutT, 2048, 2048);
  k_gemm_qkv<<<dim3(48, 32), 256, 0, stream>>>(hsb, wqkvT, bqkv, Qb, Kb, Vb);
  k_rope<<<4096, 256, 0, stream>>>(Qb, Kb);
  k_attn<<<dim3(32, 32), 256, 0, stream>>>(Qb, Kb, Vb, attnb);
  k_gemm_out<<<dim3(16, 32), 256, 0, stream>>>(attnb, woutT, bout, out);
}

// Round 3
// 463.129 us; speedup vs baseline: 1.2245x; 1.2245x over previous
//
#include <hip/hip_runtime.h>
#include <stdint.h>
#include <math.h>

typedef float  f32x4  __attribute__((ext_vector_type(4)));
typedef __bf16 bf16x8 __attribute__((ext_vector_type(8)));
typedef __bf16 bf16x4 __attribute__((ext_vector_type(4)));

#define LOG2E 1.4426950408889634f

// async global->LDS, 16B per lane. LDS side must be wave-uniform base + lane*16.
__device__ __forceinline__ void gl_lds16(const void* g, void* l) {
  __builtin_amdgcn_global_load_lds(
      (__attribute__((address_space(1))) void*)(uintptr_t)g,
      (__attribute__((address_space(3))) void*)l, 16, 0, 0);
}

// ---------------- cast fp32 -> bf16, x4 vectorized ----------------
__global__ __launch_bounds__(256) void k_cast(const float* __restrict__ in,
                                              __bf16* __restrict__ out, int n4) {
  int i = blockIdx.x * 256 + threadIdx.x;
  if (i >= n4) return;
  f32x4 v = ((const f32x4*)in)[i];
  ((bf16x4*)out)[i] = __builtin_convertvector(v, bf16x4);
}

// ---------------- transpose + cast: in [K][N] fp32 -> out [N][K] bf16 ----------------
__global__ __launch_bounds__(256) void k_transpose(const float* __restrict__ in,
                                                   __bf16* __restrict__ out,
                                                   int K, int N) {
  __shared__ float tile[32][33];
  int n0 = blockIdx.x * 32, k0 = blockIdx.y * 32;
  int tx = threadIdx.x & 31, ty = threadIdx.x >> 5;
#pragma unroll
  for (int i = 0; i < 32; i += 8)
    tile[ty + i][tx] = in[(size_t)(k0 + ty + i) * N + n0 + tx];
  __syncthreads();
#pragma unroll
  for (int i = 0; i < 32; i += 8)
    out[(size_t)(n0 + ty + i) * K + k0 + tx] = (__bf16)tile[tx][ty + i];
}

// ---------------- per-head V transpose: in [bh][2048][128] -> out [bh][128][2048] (bf16) ----------------
__global__ __launch_bounds__(256) void k_vtrans(const __bf16* __restrict__ in,
                                                __bf16* __restrict__ out) {
  __shared__ __bf16 tile[32][33];
  int bh = blockIdx.z;
  int d0 = blockIdx.x * 32, s0 = blockIdx.y * 32;
  int tx = threadIdx.x & 31, ty = threadIdx.x >> 5;
  const __bf16* ip = in + (size_t)bh * 262144;
  __bf16* op = out + (size_t)bh * 262144;
#pragma unroll
  for (int i = 0; i < 32; i += 8)
    tile[ty + i][tx] = ip[(size_t)(s0 + ty + i) * 128 + d0 + tx];
  __syncthreads();
#pragma unroll
  for (int i = 0; i < 32; i += 8)
    op[(size_t)(d0 + ty + i) * 2048 + s0 + tx] = tile[tx][ty + i];
}

// ---------------- QKV GEMM: A[4096][2048] bf16 x Bt[6144][2048] bf16 ----------------
__global__ __launch_bounds__(256) void k_gemm_qkv(
    const __bf16* __restrict__ A, const __bf16* __restrict__ Bt,
    const float* __restrict__ bias,
    __bf16* __restrict__ Qo, __bf16* __restrict__ Ko, __bf16* __restrict__ Vo) {
  __shared__ __bf16 sA[128 * 32];
  __shared__ __bf16 sB[128 * 32];
  const int K = 2048;
  int t = threadIdx.x;
  int m0 = blockIdx.y << 7, n0 = blockIdx.x << 7;
  int wave = t >> 6, lane = t & 63;
  int wr = wave >> 1, wc = wave & 1;
  int quad = lane >> 4, l16 = lane & 15;

  f32x4 acc[4][4] = {};

  const char* gA = (const char*)(A + (size_t)m0 * K);
  const char* gB = (const char*)(Bt + (size_t)n0 * K);
  int s0 = t, s1 = t + 256;
  int ar0 = s0 >> 2, ac0 = s0 & 3;
  int ar1 = s1 >> 2, ac1 = s1 & 3;

  for (int k0 = 0; k0 < K; k0 += 32) {
    gl_lds16(gA + (size_t)ar0 * 4096 + k0 * 2 + ac0 * 16, (char*)sA + s0 * 16);
    gl_lds16(gA + (size_t)ar1 * 4096 + k0 * 2 + ac1 * 16, (char*)sA + s1 * 16);
    gl_lds16(gB + (size_t)ar0 * 4096 + k0 * 2 + ac0 * 16, (char*)sB + s0 * 16);
    gl_lds16(gB + (size_t)ar1 * 4096 + k0 * 2 + ac1 * 16, (char*)sB + s1 * 16);
    asm volatile("s_waitcnt vmcnt(0)" ::: "memory");
    __syncthreads();

    bf16x8 af[4], bfr[4];
#pragma unroll
    for (int mt = 0; mt < 4; ++mt)
      af[mt] = *(const bf16x8*)(sA + (wr * 64 + mt * 16 + l16) * 32 + quad * 8);
#pragma unroll
    for (int nt = 0; nt < 4; ++nt)
      bfr[nt] = *(const bf16x8*)(sB + (wc * 64 + nt * 16 + l16) * 32 + quad * 8);
#pragma unroll
    for (int mt = 0; mt < 4; ++mt)
#pragma unroll
      for (int nt = 0; nt < 4; ++nt)
        acc[mt][nt] = __builtin_amdgcn_mfma_f32_16x16x32_bf16(af[mt], bfr[nt], acc[mt][nt], 0, 0, 0);
    __syncthreads();
  }

  // epilogue: scatter into Q/K/V [b*16+h][s][128] bf16 with bias.
#pragma unroll
  for (int mt = 0; mt < 4; ++mt) {
    int m = m0 + wr * 64 + mt * 16 + quad * 4;
#pragma unroll
    for (int nt = 0; nt < 4; ++nt) {
      int n = n0 + wc * 64 + nt * 16 + l16;
      int h = n / 384;
      int rem = n - h * 384;
      int which = rem >> 7;
      int d = rem & 127;
      __bf16* dst = (which == 0) ? Qo : (which == 1) ? Ko : Vo;
      float bz = bias[n];
#pragma unroll
      for (int r = 0; r < 4; ++r) {
        int mm = m + r;
        int b = mm >> 11, s = mm & 2047;
        dst[(((size_t)(b * 16 + h) * 2048 + s) << 7) + d] = (__bf16)(acc[mt][nt][r] + bz);
      }
    }
  }
}

// ---------------- Out-proj GEMM: attn[4096][2048] bf16 x Bt[2048][2048] bf16 -> f32 ----------------
__global__ __launch_bounds__(256) void k_gemm_out(
    const __bf16* __restrict__ A, const __bf16* __restrict__ Bt,
    const float* __restrict__ bias, float* __restrict__ Out) {
  __shared__ __bf16 sA[128 * 32];
  __shared__ __bf16 sB[128 * 32];
  const int K = 2048;
  int t = threadIdx.x;
  int m0 = blockIdx.y << 7, n0 = blockIdx.x << 7;
  int wave = t >> 6, lane = t & 63;
  int wr = wave >> 1, wc = wave & 1;
  int quad = lane >> 4, l16 = lane & 15;

  f32x4 acc[4][4] = {};

  const char* gA = (const char*)(A + (size_t)m0 * K);
  const char* gB = (const char*)(Bt + (size_t)n0 * K);
  int s0 = t, s1 = t + 256;
  int ar0 = s0 >> 2, ac0 = s0 & 3;
  int ar1 = s1 >> 2, ac1 = s1 & 3;

  for (int k0 = 0; k0 < K; k0 += 32) {
    gl_lds16(gA + (size_t)ar0 * 4096 + k0 * 2 + ac0 * 16, (char*)sA + s0 * 16);
    gl_lds16(gA + (size_t)ar1 * 4096 + k0 * 2 + ac1 * 16, (char*)sA + s1 * 16);
    gl_lds16(gB + (size_t)ar0 * 4096 + k0 * 2 + ac0 * 16, (char*)sB + s0 * 16);
    gl_lds16(gB + (size_t)ar1 * 4096 + k0 * 2 + ac1 * 16, (char*)sB + s1 * 16);
    asm volatile("s_waitcnt vmcnt(0)" ::: "memory");
    __syncthreads();

    bf16x8 af[4], bfr[4];
#pragma unroll
    for (int mt = 0; mt < 4; ++mt)
      af[mt] = *(const bf16x8*)(sA + (wr * 64 + mt * 16 + l16) * 32 + quad * 8);
#pragma unroll
    for (int nt = 0; nt < 4; ++nt)
      bfr[nt] = *(const bf16x8*)(sB + (wc * 64 + nt * 16 + l16) * 32 + quad * 8);
#pragma unroll
    for (int mt = 0; mt < 4; ++mt)
#pragma unroll
      for (int nt = 0; nt < 4; ++nt)
        acc[mt][nt] = __builtin_amdgcn_mfma_f32_16x16x32_bf16(af[mt], bfr[nt], acc[mt][nt], 0, 0, 0);
    __syncthreads();
  }

#pragma unroll
  for (int mt = 0; mt < 4; ++mt) {
    int m = m0 + wr * 64 + mt * 16 + quad * 4;
#pragma unroll
    for (int nt = 0; nt < 4; ++nt) {
      int n = n0 + wc * 64 + nt * 16 + l16;
      float bz = bias[n];
#pragma unroll
      for (int r = 0; r < 4; ++r)
        Out[(size_t)(m + r) * 2048 + n] = acc[mt][nt][r] + bz;
    }
  }
}

// ---------------- RoPE on Q and K, dims 0..31, in place ----------------
__global__ __launch_bounds__(256) void k_rope(__bf16* __restrict__ Q,
                                              __bf16* __restrict__ Kb) {
  int idx = blockIdx.x * 256 + threadIdx.x;  // [0, 32*2048*16)
  int i = idx & 15;
  int s = (idx >> 4) & 2047;
  size_t base = (size_t)(idx >> 4) * 128;
  float ang = (float)s * exp2f(-(float)i * 0.83048202372184058f);
  float sn, cs;
  sincosf(ang, &sn, &cs);
  float x1, x2;
  x1 = (float)Q[base + i]; x2 = (float)Q[base + i + 16];
  Q[base + i]      = (__bf16)(x1 * cs - x2 * sn);
  Q[base + i + 16] = (__bf16)(x2 * cs + x1 * sn);
  x1 = (float)Kb[base + i]; x2 = (float)Kb[base + i + 16];
  Kb[base + i]      = (__bf16)(x1 * cs - x2 * sn);
  Kb[base + i + 16] = (__bf16)(x2 * cs + x1 * sn);
}

// ---------------- causal flash attention ----------------
// grid (16, 32): block handles q-tiles qt and 31-qt -> uniform 33 K-iters/block.
// K and V(pre-transposed) staged via global_load_lds w/ XOR-16B-chunk swizzle:
// chunk c of row r stored at c ^ (r&7) (low 3 bits) -> B-frag ds_read_b128
// bank-group = c ^ (l16&7): all 8 groups distinct per 8 consecutive lanes.
__global__ __launch_bounds__(256) void k_attn(const __bf16* __restrict__ Qb,
                                              const __bf16* __restrict__ Kb,
                                              const __bf16* __restrict__ Vt,
                                              __bf16* __restrict__ Ob) {
  __shared__ __bf16 sK[64 * 128];   // [kv][d], swizzled 16B chunks (16/row)
  __shared__ __bf16 sV[128 * 64];   // [d][kv], swizzled 16B chunks (8/row)
  __shared__ __bf16 sP[4 * 16 * 72];
  int t = threadIdx.x, w = t >> 6, lane = t & 63;
  int quad = lane >> 4, l16 = lane & 15;
  int bh = blockIdx.y;
  size_t base = (size_t)bh * (2048 * 128);
  const char* gK = (const char*)(Kb + base);
  const char* gV = (const char*)(Vt + base);
  __bf16* sp = sP + w * (16 * 72);
  int b = bh >> 4, h = bh & 15;

  for (int ph = 0; ph < 2; ++ph) {
    int qt = (ph == 0) ? (int)blockIdx.x : 31 - (int)blockIdx.x;
    int q0 = qt * 64;

    bf16x8 aq[4];
    {
      const __bf16* qp = Qb + base + (size_t)(q0 + w * 16 + l16) * 128 + quad * 8;
#pragma unroll
      for (int kc = 0; kc < 4; ++kc) aq[kc] = *(const bf16x8*)(qp + kc * 32);
    }

    f32x4 o[8] = {};
    float mrow[4], lrow[4], alpha[4];
#pragma unroll
    for (int r = 0; r < 4; ++r) { mrow[r] = -INFINITY; lrow[r] = 0.f; }

    for (int kt = 0; kt <= qt; ++kt) {
      int kv0 = kt * 64;
      __syncthreads();  // LDS reuse vs previous iteration/phase
      // stage K tile [64 kv][128 d]: 1024 16B-chunks, swizzled
#pragma unroll
      for (int i = 0; i < 4; ++i) {
        int L = i * 256 + t;
        int row = L >> 4, sc = L & 15;
        int c = (sc & 8) | ((sc & 7) ^ (row & 7));
        gl_lds16(gK + (size_t)(kv0 + row) * 256 + c * 16, (char*)sK + L * 16);
      }
      // stage V tile [128 d][64 kv] from Vt: 1024 16B-chunks, swizzled
#pragma unroll
      for (int i = 0; i < 4; ++i) {
        int L = i * 256 + t;
        int row = L >> 3, sc = L & 7;
        int c = sc ^ (row & 7);
        gl_lds16(gV + (size_t)row * 4096 + kv0 * 2 + c * 16, (char*)sV + L * 16);
      }
      asm volatile("s_waitcnt vmcnt(0)" ::: "memory");
      __syncthreads();

      // S = Q K^T * scale  (wave: 16 q-rows x 64 kv-cols)
      float sv[4][4];
#pragma unroll
      for (int nt = 0; nt < 4; ++nt) {
        f32x4 z = {};
#pragma unroll
        for (int kc = 0; kc < 4; ++kc) {
          int sc = ((kc & 2) << 2) | (((((kc & 1) << 2) | quad)) ^ (l16 & 7));
          bf16x8 bk = *(const bf16x8*)(sK + (nt * 16 + l16) * 128 + sc * 8);
          z = __builtin_amdgcn_mfma_f32_16x16x32_bf16(aq[kc], bk, z, 0, 0, 0);
        }
#pragma unroll
        for (int r = 0; r < 4; ++r) sv[nt][r] = z[r] * 0.08838834764831845f;
      }
      if (kt == qt) {  // diagonal tile: causal mask
#pragma unroll
        for (int nt = 0; nt < 4; ++nt) {
          int col = kv0 + nt * 16 + l16;
#pragma unroll
          for (int r = 0; r < 4; ++r) {
            int row = q0 + w * 16 + quad * 4 + r;
            if (col > row) sv[nt][r] = -1e9f;
          }
        }
      }
      // online softmax
#pragma unroll
      for (int r = 0; r < 4; ++r) {
        float mx = fmaxf(fmaxf(sv[0][r], sv[1][r]), fmaxf(sv[2][r], sv[3][r]));
#pragma unroll
        for (int off = 1; off < 16; off <<= 1) mx = fmaxf(mx, __shfl_xor(mx, off, 64));
        float mnew = fmaxf(mrow[r], mx);
        alpha[r] = exp2f((mrow[r] - mnew) * LOG2E);
        mrow[r] = mnew;
        float rs = 0.f;
#pragma unroll
        for (int nt = 0; nt < 4; ++nt) {
          float p = exp2f((sv[nt][r] - mnew) * LOG2E);
          sv[nt][r] = p;
          rs += p;
        }
#pragma unroll
        for (int off = 1; off < 16; off <<= 1) rs += __shfl_xor(rs, off, 64);
        lrow[r] = lrow[r] * alpha[r] + rs;
      }
      // P (C-layout) -> LDS -> A-layout (wave-private region)
#pragma unroll
      for (int nt = 0; nt < 4; ++nt)
#pragma unroll
        for (int r = 0; r < 4; ++r)
          sp[(quad * 4 + r) * 72 + nt * 16 + l16] = (__bf16)sv[nt][r];
#pragma unroll
      for (int nt = 0; nt < 8; ++nt)
#pragma unroll
        for (int r = 0; r < 4; ++r) o[nt][r] *= alpha[r];
      asm volatile("s_waitcnt lgkmcnt(0)" ::: "memory");
      // O += P V
#pragma unroll
      for (int kc = 0; kc < 2; ++kc) {
        bf16x8 ap = *(const bf16x8*)(sp + l16 * 72 + kc * 32 + quad * 8);
#pragma unroll
        for (int nt = 0; nt < 8; ++nt) {
          int sc = ((kc << 2) | quad) ^ (l16 & 7);
          bf16x8 bv = *(const bf16x8*)(sV + (nt * 16 + l16) * 64 + sc * 8);
          o[nt] = __builtin_amdgcn_mfma_f32_16x16x32_bf16(ap, bv, o[nt], 0, 0, 0);
        }
      }
    }

    // epilogue: O/l -> attn buffer [b][s][h][d] bf16
#pragma unroll
    for (int r = 0; r < 4; ++r) {
      float inv = 1.f / lrow[r];
      int srow = q0 + w * 16 + quad * 4 + r;
      __bf16* op = Ob + ((size_t)((b * 2048 + srow) * 16 + h)) * 128;
#pragma unroll
      for (int nt = 0; nt < 8; ++nt)
        op[nt * 16 + l16] = (__bf16)(o[nt][r] * inv);
    }
  }
}

extern "C" void kernel_launch(void* const* d_in, const int* in_sizes, int n_in,
                              void* d_out, int out_size, void* d_ws, size_t ws_size,
                              hipStream_t stream) {
  const float* hs   = (const float*)d_in[0];
  const float* wqkv = (const float*)d_in[2];
  const float* bqkv = (const float*)d_in[3];
  const float* wout = (const float*)d_in[4];
  const float* bout = (const float*)d_in[5];
  float* out = (float*)d_out;

  char* ws = (char*)d_ws;
  __bf16* hsb   = (__bf16*)(ws);                // [4096][2048]; reused as attnb
  __bf16* attnb = (__bf16*)(ws);
  __bf16* wqkvT = (__bf16*)(ws + 16777216);     // [6144][2048]; dead after gemm_qkv
  __bf16* Vt    = (__bf16*)(ws + 16777216);     // [32][128][2048]; reuses wqkvT region
  __bf16* woutT = (__bf16*)(ws + 41943040);     // [2048][2048]
  __bf16* Qb    = (__bf16*)(ws + 50331648);     // [32][2048][128]
  __bf16* Kb    = (__bf16*)(ws + 67108864);
  __bf16* Vo    = (__bf16*)(ws + 83886080);
  // total ws use: 100,663,296 B

  k_cast<<<8192, 256, 0, stream>>>(hs, hsb, 2097152);
  k_transpose<<<dim3(192, 64), 256, 0, stream>>>(wqkv, wqkvT, 2048, 6144);
  k_transpose<<<dim3(64, 64), 256, 0, stream>>>(wout, woutT, 2048, 2048);
  k_gemm_qkv<<<dim3(48, 32), 256, 0, stream>>>(hsb, wqkvT, bqkv, Qb, Kb, Vo);
  k_rope<<<4096, 256, 0, stream>>>(Qb, Kb);
  k_vtrans<<<dim3(4, 64, 32), 256, 0, stream>>>(Vo, Vt);
  k_attn<<<dim3(16, 32), 256, 0, stream>>>(Qb, Kb, Vt, attnb);
  k_gemm_out<<<dim3(16, 32), 256, 0, stream>>>(attnb, woutT, bout, out);
}

// Round 4
// 435.985 us; speedup vs baseline: 1.3008x; 1.0623x over previous
//
#include <hip/hip_runtime.h>
#include <stdint.h>
#include <math.h>

typedef float  f32x4  __attribute__((ext_vector_type(4)));
typedef __bf16 bf16x8 __attribute__((ext_vector_type(8)));
typedef __bf16 bf16x4 __attribute__((ext_vector_type(4)));

#define LOG2E 1.4426950408889634f

// async global->LDS, 16B per lane. LDS side must be wave-uniform base + lane*16.
__device__ __forceinline__ void gl_lds16(const void* g, void* l) {
  __builtin_amdgcn_global_load_lds(
      (__attribute__((address_space(1))) void*)(uintptr_t)g,
      (__attribute__((address_space(3))) void*)l, 16, 0, 0);
}

// ---------------- cast fp32 -> bf16, x4 vectorized ----------------
__global__ __launch_bounds__(256) void k_cast(const float* __restrict__ in,
                                              __bf16* __restrict__ out, int n4) {
  int i = blockIdx.x * 256 + threadIdx.x;
  if (i >= n4) return;
  f32x4 v = ((const f32x4*)in)[i];
  ((bf16x4*)out)[i] = __builtin_convertvector(v, bf16x4);
}

// ---------------- transpose + cast: in [K][N] fp32 -> out [N][K] bf16 ----------------
__global__ __launch_bounds__(256) void k_transpose(const float* __restrict__ in,
                                                   __bf16* __restrict__ out,
                                                   int K, int N) {
  __shared__ float tile[32][33];
  int n0 = blockIdx.x * 32, k0 = blockIdx.y * 32;
  int tx = threadIdx.x & 31, ty = threadIdx.x >> 5;
#pragma unroll
  for (int i = 0; i < 32; i += 8)
    tile[ty + i][tx] = in[(size_t)(k0 + ty + i) * N + n0 + tx];
  __syncthreads();
#pragma unroll
  for (int i = 0; i < 32; i += 8)
    out[(size_t)(n0 + ty + i) * K + k0 + tx] = (__bf16)tile[tx][ty + i];
}

// ---------------- per-head V transpose: in [bh][2048][128] -> out [bh][128][2048] (bf16) ----------------
__global__ __launch_bounds__(256) void k_vtrans(const __bf16* __restrict__ in,
                                                __bf16* __restrict__ out) {
  __shared__ __bf16 tile[32][33];
  int bh = blockIdx.z;
  int d0 = blockIdx.x * 32, s0 = blockIdx.y * 32;
  int tx = threadIdx.x & 31, ty = threadIdx.x >> 5;
  const __bf16* ip = in + (size_t)bh * 262144;
  __bf16* op = out + (size_t)bh * 262144;
#pragma unroll
  for (int i = 0; i < 32; i += 8)
    tile[ty + i][tx] = ip[(size_t)(s0 + ty + i) * 128 + d0 + tx];
  __syncthreads();
#pragma unroll
  for (int i = 0; i < 32; i += 8)
    op[(size_t)(d0 + ty + i) * 2048 + s0 + tx] = tile[tx][ty + i];
}

// ---------------- QKV GEMM: A[4096][2048] bf16 x Bt[6144][2048] bf16 ----------------
// 128x128 tile, BK=64 (32 MFMA/barrier), XOR-16B-chunk swizzle on sA/sB:
// chunk c of row r stored at slot c^(r&7) -> fragment ds_read_b128 bank-group
// = (s*4+quad)^(l16&7): all 8 groups distinct per 8 lanes -> conflict-free.
__global__ __launch_bounds__(256) void k_gemm_qkv(
    const __bf16* __restrict__ A, const __bf16* __restrict__ Bt,
    const float* __restrict__ bias,
    __bf16* __restrict__ Qo, __bf16* __restrict__ Ko, __bf16* __restrict__ Vo) {
  __shared__ __bf16 sA[128 * 64];
  __shared__ __bf16 sB[128 * 64];
  const int K = 2048;
  int t = threadIdx.x;
  int m0 = blockIdx.y << 7, n0 = blockIdx.x << 7;
  int wave = t >> 6, lane = t & 63;
  int wr = wave >> 1, wc = wave & 1;
  int quad = lane >> 4, l16 = lane & 15, x7 = lane & 7;

  f32x4 acc[4][4] = {};

  const char* gA = (const char*)(A + (size_t)m0 * K);
  const char* gB = (const char*)(Bt + (size_t)n0 * K);

  int srcoff[4], ldsoff[4];
#pragma unroll
  for (int i = 0; i < 4; ++i) {
    int L = i * 256 + t;
    int row = L >> 3, sc = L & 7;
    int c = sc ^ (row & 7);
    srcoff[i] = row * 4096 + c * 16;  // bytes (row stride K*2 = 4096)
    ldsoff[i] = L * 16;
  }

  for (int k0 = 0; k0 < K; k0 += 64) {
#pragma unroll
    for (int i = 0; i < 4; ++i)
      gl_lds16(gA + (size_t)(srcoff[i] + k0 * 2), (char*)sA + ldsoff[i]);
#pragma unroll
    for (int i = 0; i < 4; ++i)
      gl_lds16(gB + (size_t)(srcoff[i] + k0 * 2), (char*)sB + ldsoff[i]);
    asm volatile("s_waitcnt vmcnt(0)" ::: "memory");
    __syncthreads();

#pragma unroll
    for (int s = 0; s < 2; ++s) {
      int slot = ((s << 2) | quad) ^ x7;
      bf16x8 af[4], bfr[4];
#pragma unroll
      for (int mt = 0; mt < 4; ++mt)
        af[mt] = *(const bf16x8*)(sA + (wr * 64 + mt * 16 + l16) * 64 + slot * 8);
#pragma unroll
      for (int nt = 0; nt < 4; ++nt)
        bfr[nt] = *(const bf16x8*)(sB + (wc * 64 + nt * 16 + l16) * 64 + slot * 8);
#pragma unroll
      for (int mt = 0; mt < 4; ++mt)
#pragma unroll
        for (int nt = 0; nt < 4; ++nt)
          acc[mt][nt] = __builtin_amdgcn_mfma_f32_16x16x32_bf16(af[mt], bfr[nt], acc[mt][nt], 0, 0, 0);
    }
    __syncthreads();
  }

  // epilogue: scatter into Q/K/V [b*16+h][s][128] bf16 with bias.
#pragma unroll
  for (int mt = 0; mt < 4; ++mt) {
    int m = m0 + wr * 64 + mt * 16 + quad * 4;
#pragma unroll
    for (int nt = 0; nt < 4; ++nt) {
      int n = n0 + wc * 64 + nt * 16 + l16;
      int h = n / 384;
      int rem = n - h * 384;
      int which = rem >> 7;
      int d = rem & 127;
      __bf16* dst = (which == 0) ? Qo : (which == 1) ? Ko : Vo;
      float bz = bias[n];
#pragma unroll
      for (int r = 0; r < 4; ++r) {
        int mm = m + r;
        int b = mm >> 11, s = mm & 2047;
        dst[(((size_t)(b * 16 + h) * 2048 + s) << 7) + d] = (__bf16)(acc[mt][nt][r] + bz);
      }
    }
  }
}

// ---------------- Out-proj GEMM: attn[4096][2048] bf16 x Bt[2048][2048] bf16 -> f32 ----------------
__global__ __launch_bounds__(256) void k_gemm_out(
    const __bf16* __restrict__ A, const __bf16* __restrict__ Bt,
    const float* __restrict__ bias, float* __restrict__ Out) {
  __shared__ __bf16 sA[128 * 64];
  __shared__ __bf16 sB[128 * 64];
  const int K = 2048;
  int t = threadIdx.x;
  int m0 = blockIdx.y << 7, n0 = blockIdx.x << 7;
  int wave = t >> 6, lane = t & 63;
  int wr = wave >> 1, wc = wave & 1;
  int quad = lane >> 4, l16 = lane & 15, x7 = lane & 7;

  f32x4 acc[4][4] = {};

  const char* gA = (const char*)(A + (size_t)m0 * K);
  const char* gB = (const char*)(Bt + (size_t)n0 * K);

  int srcoff[4], ldsoff[4];
#pragma unroll
  for (int i = 0; i < 4; ++i) {
    int L = i * 256 + t;
    int row = L >> 3, sc = L & 7;
    int c = sc ^ (row & 7);
    srcoff[i] = row * 4096 + c * 16;
    ldsoff[i] = L * 16;
  }

  for (int k0 = 0; k0 < K; k0 += 64) {
#pragma unroll
    for (int i = 0; i < 4; ++i)
      gl_lds16(gA + (size_t)(srcoff[i] + k0 * 2), (char*)sA + ldsoff[i]);
#pragma unroll
    for (int i = 0; i < 4; ++i)
      gl_lds16(gB + (size_t)(srcoff[i] + k0 * 2), (char*)sB + ldsoff[i]);
    asm volatile("s_waitcnt vmcnt(0)" ::: "memory");
    __syncthreads();

#pragma unroll
    for (int s = 0; s < 2; ++s) {
      int slot = ((s << 2) | quad) ^ x7;
      bf16x8 af[4], bfr[4];
#pragma unroll
      for (int mt = 0; mt < 4; ++mt)
        af[mt] = *(const bf16x8*)(sA + (wr * 64 + mt * 16 + l16) * 64 + slot * 8);
#pragma unroll
      for (int nt = 0; nt < 4; ++nt)
        bfr[nt] = *(const bf16x8*)(sB + (wc * 64 + nt * 16 + l16) * 64 + slot * 8);
#pragma unroll
      for (int mt = 0; mt < 4; ++mt)
#pragma unroll
        for (int nt = 0; nt < 4; ++nt)
          acc[mt][nt] = __builtin_amdgcn_mfma_f32_16x16x32_bf16(af[mt], bfr[nt], acc[mt][nt], 0, 0, 0);
    }
    __syncthreads();
  }

#pragma unroll
  for (int mt = 0; mt < 4; ++mt) {
    int m = m0 + wr * 64 + mt * 16 + quad * 4;
#pragma unroll
    for (int nt = 0; nt < 4; ++nt) {
      int n = n0 + wc * 64 + nt * 16 + l16;
      float bz = bias[n];
#pragma unroll
      for (int r = 0; r < 4; ++r)
        Out[(size_t)(m + r) * 2048 + n] = acc[mt][nt][r] + bz;
    }
  }
}

// ---------------- RoPE on Q and K, dims 0..31, in place ----------------
__global__ __launch_bounds__(256) void k_rope(__bf16* __restrict__ Q,
                                              __bf16* __restrict__ Kb) {
  int idx = blockIdx.x * 256 + threadIdx.x;  // [0, 32*2048*16)
  int i = idx & 15;
  int s = (idx >> 4) & 2047;
  size_t base = (size_t)(idx >> 4) * 128;
  float ang = (float)s * exp2f(-(float)i * 0.83048202372184058f);
  float sn, cs;
  sincosf(ang, &sn, &cs);
  float x1, x2;
  x1 = (float)Q[base + i]; x2 = (float)Q[base + i + 16];
  Q[base + i]      = (__bf16)(x1 * cs - x2 * sn);
  Q[base + i + 16] = (__bf16)(x2 * cs + x1 * sn);
  x1 = (float)Kb[base + i]; x2 = (float)Kb[base + i + 16];
  Kb[base + i]      = (__bf16)(x1 * cs - x2 * sn);
  Kb[base + i + 16] = (__bf16)(x2 * cs + x1 * sn);
}

// ---------------- causal flash attention ----------------
// grid (16, 32): block handles q-tiles qt and 31-qt -> uniform 33 K-iters/block.
// K and V(pre-transposed) staged via global_load_lds w/ XOR-16B-chunk swizzle.
__global__ __launch_bounds__(256) void k_attn(const __bf16* __restrict__ Qb,
                                              const __bf16* __restrict__ Kb,
                                              const __bf16* __restrict__ Vt,
                                              __bf16* __restrict__ Ob) {
  __shared__ __bf16 sK[64 * 128];   // [kv][d], swizzled 16B chunks (16/row)
  __shared__ __bf16 sV[128 * 64];   // [d][kv], swizzled 16B chunks (8/row)
  __shared__ __bf16 sP[4 * 16 * 72];
  int t = threadIdx.x, w = t >> 6, lane = t & 63;
  int quad = lane >> 4, l16 = lane & 15;
  int bh = blockIdx.y;
  size_t base = (size_t)bh * (2048 * 128);
  const char* gK = (const char*)(Kb + base);
  const char* gV = (const char*)(Vt + base);
  __bf16* sp = sP + w * (16 * 72);
  int b = bh >> 4, h = bh & 15;

  for (int ph = 0; ph < 2; ++ph) {
    int qt = (ph == 0) ? (int)blockIdx.x : 31 - (int)blockIdx.x;
    int q0 = qt * 64;

    bf16x8 aq[4];
    {
      const __bf16* qp = Qb + base + (size_t)(q0 + w * 16 + l16) * 128 + quad * 8;
#pragma unroll
      for (int kc = 0; kc < 4; ++kc) aq[kc] = *(const bf16x8*)(qp + kc * 32);
    }

    f32x4 o[8] = {};
    float mrow[4], lrow[4], alpha[4];
#pragma unroll
    for (int r = 0; r < 4; ++r) { mrow[r] = -INFINITY; lrow[r] = 0.f; }

    for (int kt = 0; kt <= qt; ++kt) {
      int kv0 = kt * 64;
      __syncthreads();  // LDS reuse vs previous iteration/phase
#pragma unroll
      for (int i = 0; i < 4; ++i) {
        int L = i * 256 + t;
        int row = L >> 4, sc = L & 15;
        int c = (sc & 8) | ((sc & 7) ^ (row & 7));
        gl_lds16(gK + (size_t)(kv0 + row) * 256 + c * 16, (char*)sK + L * 16);
      }
#pragma unroll
      for (int i = 0; i < 4; ++i) {
        int L = i * 256 + t;
        int row = L >> 3, sc = L & 7;
        int c = sc ^ (row & 7);
        gl_lds16(gV + (size_t)row * 4096 + kv0 * 2 + c * 16, (char*)sV + L * 16);
      }
      asm volatile("s_waitcnt vmcnt(0)" ::: "memory");
      __syncthreads();

      // S = Q K^T * scale  (wave: 16 q-rows x 64 kv-cols)
      float sv[4][4];
#pragma unroll
      for (int nt = 0; nt < 4; ++nt) {
        f32x4 z = {};
#pragma unroll
        for (int kc = 0; kc < 4; ++kc) {
          int sc = ((kc & 2) << 2) | (((((kc & 1) << 2) | quad)) ^ (l16 & 7));
          bf16x8 bk = *(const bf16x8*)(sK + (nt * 16 + l16) * 128 + sc * 8);
          z = __builtin_amdgcn_mfma_f32_16x16x32_bf16(aq[kc], bk, z, 0, 0, 0);
        }
#pragma unroll
        for (int r = 0; r < 4; ++r) sv[nt][r] = z[r] * 0.08838834764831845f;
      }
      if (kt == qt) {  // diagonal tile: causal mask
#pragma unroll
        for (int nt = 0; nt < 4; ++nt) {
          int col = kv0 + nt * 16 + l16;
#pragma unroll
          for (int r = 0; r < 4; ++r) {
            int row = q0 + w * 16 + quad * 4 + r;
            if (col > row) sv[nt][r] = -1e9f;
          }
        }
      }
      // online softmax
#pragma unroll
      for (int r = 0; r < 4; ++r) {
        float mx = fmaxf(fmaxf(sv[0][r], sv[1][r]), fmaxf(sv[2][r], sv[3][r]));
#pragma unroll
        for (int off = 1; off < 16; off <<= 1) mx = fmaxf(mx, __shfl_xor(mx, off, 64));
        float mnew = fmaxf(mrow[r], mx);
        alpha[r] = exp2f((mrow[r] - mnew) * LOG2E);
        mrow[r] = mnew;
        float rs = 0.f;
#pragma unroll
        for (int nt = 0; nt < 4; ++nt) {
          float p = exp2f((sv[nt][r] - mnew) * LOG2E);
          sv[nt][r] = p;
          rs += p;
        }
#pragma unroll
        for (int off = 1; off < 16; off <<= 1) rs += __shfl_xor(rs, off, 64);
        lrow[r] = lrow[r] * alpha[r] + rs;
      }
      // P (C-layout) -> LDS -> A-layout (wave-private region)
#pragma unroll
      for (int nt = 0; nt < 4; ++nt)
#pragma unroll
        for (int r = 0; r < 4; ++r)
          sp[(quad * 4 + r) * 72 + nt * 16 + l16] = (__bf16)sv[nt][r];
#pragma unroll
      for (int nt = 0; nt < 8; ++nt)
#pragma unroll
        for (int r = 0; r < 4; ++r) o[nt][r] *= alpha[r];
      asm volatile("s_waitcnt lgkmcnt(0)" ::: "memory");
      // O += P V
#pragma unroll
      for (int kc = 0; kc < 2; ++kc) {
        bf16x8 ap = *(const bf16x8*)(sp + l16 * 72 + kc * 32 + quad * 8);
#pragma unroll
        for (int nt = 0; nt < 8; ++nt) {
          int sc = ((kc << 2) | quad) ^ (l16 & 7);
          bf16x8 bv = *(const bf16x8*)(sV + (nt * 16 + l16) * 64 + sc * 8);
          o[nt] = __builtin_amdgcn_mfma_f32_16x16x32_bf16(ap, bv, o[nt], 0, 0, 0);
        }
      }
    }

    // epilogue: O/l -> attn buffer [b][s][h][d] bf16
#pragma unroll
    for (int r = 0; r < 4; ++r) {
      float inv = 1.f / lrow[r];
      int srow = q0 + w * 16 + quad * 4 + r;
      __bf16* op = Ob + ((size_t)((b * 2048 + srow) * 16 + h)) * 128;
#pragma unroll
      for (int nt = 0; nt < 8; ++nt)
        op[nt * 16 + l16] = (__bf16)(o[nt][r] * inv);
    }
  }
}

extern "C" void kernel_launch(void* const* d_in, const int* in_sizes, int n_in,
                              void* d_out, int out_size, void* d_ws, size_t ws_size,
                              hipStream_t stream) {
  const float* hs   = (const float*)d_in[0];
  const float* wqkv = (const float*)d_in[2];
  const float* bqkv = (const float*)d_in[3];
  const float* wout = (const float*)d_in[4];
  const float* bout = (const float*)d_in[5];
  float* out = (float*)d_out;

  char* ws = (char*)d_ws;
  __bf16* hsb   = (__bf16*)(ws);                // [4096][2048]; reused as attnb
  __bf16* attnb = (__bf16*)(ws);
  __bf16* wqkvT = (__bf16*)(ws + 16777216);     // [6144][2048]; dead after gemm_qkv
  __bf16* Vt    = (__bf16*)(ws + 16777216);     // [32][128][2048]; reuses wqkvT region
  __bf16* woutT = (__bf16*)(ws + 41943040);     // [2048][2048]
  __bf16* Qb    = (__bf16*)(ws + 50331648);     // [32][2048][128]
  __bf16* Kb    = (__bf16*)(ws + 67108864);
  __bf16* Vo    = (__bf16*)(ws + 83886080);
  // total ws use: 100,663,296 B

  k_cast<<<8192, 256, 0, stream>>>(hs, hsb, 2097152);
  k_transpose<<<dim3(192, 64), 256, 0, stream>>>(wqkv, wqkvT, 2048, 6144);
  k_transpose<<<dim3(64, 64), 256, 0, stream>>>(wout, woutT, 2048, 2048);
  k_gemm_qkv<<<dim3(48, 32), 256, 0, stream>>>(hsb, wqkvT, bqkv, Qb, Kb, Vo);
  k_rope<<<4096, 256, 0, stream>>>(Qb, Kb);
  k_vtrans<<<dim3(4, 64, 32), 256, 0, stream>>>(Vo, Vt);
  k_attn<<<dim3(16, 32), 256, 0, stream>>>(Qb, Kb, Vt, attnb);
  k_gemm_out<<<dim3(16, 32), 256, 0, stream>>>(attnb, woutT, bout, out);
}

// Round 5
// 426.366 us; speedup vs baseline: 1.3301x; 1.0226x over previous
//
#include <hip/hip_runtime.h>
#include <stdint.h>
#include <math.h>

typedef float  f32x4  __attribute__((ext_vector_type(4)));
typedef __bf16 bf16x8 __attribute__((ext_vector_type(8)));
typedef __bf16 bf16x4 __attribute__((ext_vector_type(4)));

// async global->LDS, 16B per lane. LDS side must be wave-uniform base + lane*16.
__device__ __forceinline__ void gl_lds16(const void* g, void* l) {
  __builtin_amdgcn_global_load_lds(
      (__attribute__((address_space(1))) void*)(uintptr_t)g,
      (__attribute__((address_space(3))) void*)l, 16, 0, 0);
}

// ---------------- cast fp32 -> bf16, x4 vectorized ----------------
__global__ __launch_bounds__(256) void k_cast(const float* __restrict__ in,
                                              __bf16* __restrict__ out, int n4) {
  int i = blockIdx.x * 256 + threadIdx.x;
  if (i >= n4) return;
  f32x4 v = ((const f32x4*)in)[i];
  ((bf16x4*)out)[i] = __builtin_convertvector(v, bf16x4);
}

// ---------------- both weight transposes in one kernel ----------------
// A: wqkv [2048][6144] -> [6144][2048]; B: wout [2048][2048] -> [2048][2048].
__global__ __launch_bounds__(256) void k_transpose2(const float* __restrict__ inA,
                                                    __bf16* __restrict__ outA,
                                                    const float* __restrict__ inB,
                                                    __bf16* __restrict__ outB) {
  __shared__ float tile[32][33];
  int bx = blockIdx.x;
  const float* in; __bf16* out; int N, n0;
  if (bx < 192) { in = inA; out = outA; N = 6144; n0 = bx * 32; }
  else          { in = inB; out = outB; N = 2048; n0 = (bx - 192) * 32; }
  const int K = 2048;
  int k0 = blockIdx.y * 32;
  int tx = threadIdx.x & 31, ty = threadIdx.x >> 5;
#pragma unroll
  for (int i = 0; i < 32; i += 8)
    tile[ty + i][tx] = in[(size_t)(k0 + ty + i) * N + n0 + tx];
  __syncthreads();
#pragma unroll
  for (int i = 0; i < 32; i += 8)
    out[(size_t)(n0 + ty + i) * K + k0 + tx] = (__bf16)tile[tx][ty + i];
}

// ---------------- QKV GEMM + fused RoPE + fused V-transpose ----------------
// 128x128 tile, BK=64, XOR-16B-chunk swizzle (conflict-free fragment reads).
// Epilogue: Q/K -> [bh][s][128] with in-register RoPE on d<32 (pairs d,d+16 are
// acc[mt][0]/acc[mt][1] of the same lane when wc==0); V -> Vt [bh][128][2048].
__global__ __launch_bounds__(256) void k_gemm_qkv(
    const __bf16* __restrict__ A, const __bf16* __restrict__ Bt,
    const float* __restrict__ bias,
    __bf16* __restrict__ Qo, __bf16* __restrict__ Ko, __bf16* __restrict__ Vt) {
  __shared__ __bf16 sA[128 * 64];
  __shared__ __bf16 sB[128 * 64];
  const int K = 2048;
  int t = threadIdx.x;
  int m0 = blockIdx.y << 7, n0 = blockIdx.x << 7;
  int wave = t >> 6, lane = t & 63;
  int wr = wave >> 1, wc = wave & 1;
  int quad = lane >> 4, l16 = lane & 15, x7 = lane & 7;

  f32x4 acc[4][4] = {};

  const char* gA = (const char*)(A + (size_t)m0 * K);
  const char* gB = (const char*)(Bt + (size_t)n0 * K);

  int srcoff[4], ldsoff[4];
#pragma unroll
  for (int i = 0; i < 4; ++i) {
    int L = i * 256 + t;
    int row = L >> 3, sc = L & 7;
    int c = sc ^ (row & 7);
    srcoff[i] = row * 4096 + c * 16;
    ldsoff[i] = L * 16;
  }

  for (int k0 = 0; k0 < K; k0 += 64) {
#pragma unroll
    for (int i = 0; i < 4; ++i)
      gl_lds16(gA + (size_t)(srcoff[i] + k0 * 2), (char*)sA + ldsoff[i]);
#pragma unroll
    for (int i = 0; i < 4; ++i)
      gl_lds16(gB + (size_t)(srcoff[i] + k0 * 2), (char*)sB + ldsoff[i]);
    asm volatile("s_waitcnt vmcnt(0)" ::: "memory");
    __syncthreads();

#pragma unroll
    for (int s = 0; s < 2; ++s) {
      int slot = ((s << 2) | quad) ^ x7;
      bf16x8 af[4], bfr[4];
#pragma unroll
      for (int mt = 0; mt < 4; ++mt)
        af[mt] = *(const bf16x8*)(sA + (wr * 64 + mt * 16 + l16) * 64 + slot * 8);
#pragma unroll
      for (int nt = 0; nt < 4; ++nt)
        bfr[nt] = *(const bf16x8*)(sB + (wc * 64 + nt * 16 + l16) * 64 + slot * 8);
#pragma unroll
      for (int mt = 0; mt < 4; ++mt)
#pragma unroll
        for (int nt = 0; nt < 4; ++nt)
          acc[mt][nt] = __builtin_amdgcn_mfma_f32_16x16x32_bf16(af[mt], bfr[nt], acc[mt][nt], 0, 0, 0);
    }
    __syncthreads();
  }

  // epilogue
  float invf = exp2f(-(float)l16 * 0.83048202372184058f);  // 10000^(-l16/16)
#pragma unroll
  for (int mt = 0; mt < 4; ++mt) {
    int m = m0 + wr * 64 + mt * 16 + quad * 4;
#pragma unroll
    for (int nt = 0; nt < 4; ++nt) {
      int n = n0 + wc * 64 + nt * 16 + l16;
      int h = n / 384;                 // wave-uniform (16-wide aligned range)
      int rem = n - h * 384;
      int which = rem >> 7;
      int d = rem & 127;               // == wc*64 + nt*16 + l16
      float bz = bias[n];
      if (which == 2) {
        // V: write transposed into Vt [bh][d][s]
#pragma unroll
        for (int r = 0; r < 4; ++r) {
          int mm = m + r; int b2 = mm >> 11; int s = mm & 2047;
          Vt[((size_t)(b2 * 16 + h) * 128 + d) * 2048 + s] = (__bf16)(acc[mt][nt][r] + bz);
        }
      } else if (wc == 0 && nt < 2) {
        if (nt == 0) {  // RoPE pair: this lane holds d=l16 (nt=0) and d=l16+16 (nt=1)
          float bz1 = bias[n + 16];
          __bf16* dst = (which == 0) ? Qo : Ko;
#pragma unroll
          for (int r = 0; r < 4; ++r) {
            int mm = m + r; int b2 = mm >> 11; int s = mm & 2047;
            float ang = (float)s * invf;
            float sn, cs;
            sincosf(ang, &sn, &cs);
            float x1 = acc[mt][0][r] + bz;
            float x2 = acc[mt][1][r] + bz1;
            size_t off = ((size_t)(b2 * 16 + h) * 2048 + s) << 7;
            dst[off + d]      = (__bf16)(x1 * cs - x2 * sn);
            dst[off + d + 16] = (__bf16)(x2 * cs + x1 * sn);
          }
        }  // nt==1 handled with nt==0
      } else {
        __bf16* dst = (which == 0) ? Qo : Ko;
#pragma unroll
        for (int r = 0; r < 4; ++r) {
          int mm = m + r; int b2 = mm >> 11; int s = mm & 2047;
          dst[(((size_t)(b2 * 16 + h) * 2048 + s) << 7) + d] = (__bf16)(acc[mt][nt][r] + bz);
        }
      }
    }
  }
}

// ---------------- Out-proj GEMM: attn[4096][2048] bf16 x Bt[2048][2048] bf16 -> f32 ----------------
__global__ __launch_bounds__(256) void k_gemm_out(
    const __bf16* __restrict__ A, const __bf16* __restrict__ Bt,
    const float* __restrict__ bias, float* __restrict__ Out) {
  __shared__ __bf16 sA[128 * 64];
  __shared__ __bf16 sB[128 * 64];
  const int K = 2048;
  int t = threadIdx.x;
  int m0 = blockIdx.y << 7, n0 = blockIdx.x << 7;
  int wave = t >> 6, lane = t & 63;
  int wr = wave >> 1, wc = wave & 1;
  int quad = lane >> 4, l16 = lane & 15, x7 = lane & 7;

  f32x4 acc[4][4] = {};

  const char* gA = (const char*)(A + (size_t)m0 * K);
  const char* gB = (const char*)(Bt + (size_t)n0 * K);

  int srcoff[4], ldsoff[4];
#pragma unroll
  for (int i = 0; i < 4; ++i) {
    int L = i * 256 + t;
    int row = L >> 3, sc = L & 7;
    int c = sc ^ (row & 7);
    srcoff[i] = row * 4096 + c * 16;
    ldsoff[i] = L * 16;
  }

  for (int k0 = 0; k0 < K; k0 += 64) {
#pragma unroll
    for (int i = 0; i < 4; ++i)
      gl_lds16(gA + (size_t)(srcoff[i] + k0 * 2), (char*)sA + ldsoff[i]);
#pragma unroll
    for (int i = 0; i < 4; ++i)
      gl_lds16(gB + (size_t)(srcoff[i] + k0 * 2), (char*)sB + ldsoff[i]);
    asm volatile("s_waitcnt vmcnt(0)" ::: "memory");
    __syncthreads();

#pragma unroll
    for (int s = 0; s < 2; ++s) {
      int slot = ((s << 2) | quad) ^ x7;
      bf16x8 af[4], bfr[4];
#pragma unroll
      for (int mt = 0; mt < 4; ++mt)
        af[mt] = *(const bf16x8*)(sA + (wr * 64 + mt * 16 + l16) * 64 + slot * 8);
#pragma unroll
      for (int nt = 0; nt < 4; ++nt)
        bfr[nt] = *(const bf16x8*)(sB + (wc * 64 + nt * 16 + l16) * 64 + slot * 8);
#pragma unroll
      for (int mt = 0; mt < 4; ++mt)
#pragma unroll
        for (int nt = 0; nt < 4; ++nt)
          acc[mt][nt] = __builtin_amdgcn_mfma_f32_16x16x32_bf16(af[mt], bfr[nt], acc[mt][nt], 0, 0, 0);
    }
    __syncthreads();
  }

#pragma unroll
  for (int mt = 0; mt < 4; ++mt) {
    int m = m0 + wr * 64 + mt * 16 + quad * 4;
#pragma unroll
    for (int nt = 0; nt < 4; ++nt) {
      int n = n0 + wc * 64 + nt * 16 + l16;
      float bz = bias[n];
#pragma unroll
      for (int r = 0; r < 4; ++r)
        Out[(size_t)(m + r) * 2048 + n] = acc[mt][nt][r] + bz;
    }
  }
}

// ---------------- causal flash attention ----------------
// grid (16, 32): block handles q-tiles qt and 31-qt -> uniform 33 K-iters/block.
// Scores pre-scaled by log2e (exp2 path, no per-exp mul). Row-sum l computed by
// MFMA via a ones-column appended to sV (rows 128..143) -> no sum shuffles.
__global__ __launch_bounds__(256) void k_attn(const __bf16* __restrict__ Qb,
                                              const __bf16* __restrict__ Kb,
                                              const __bf16* __restrict__ Vt,
                                              __bf16* __restrict__ Ob) {
  __shared__ __bf16 sK[64 * 128];    // [kv][d], swizzled 16B chunks
  __shared__ __bf16 sV[144 * 64];    // [d][kv], swizzled; rows 128..143 = 1.0
  __shared__ __bf16 sP[4 * 16 * 72];
  const float SCL = 0.08838834764831845f * 1.4426950408889634f;  // 1/sqrt(128)*log2e
  int t = threadIdx.x, w = t >> 6, lane = t & 63;
  int quad = lane >> 4, l16 = lane & 15;
  int bh = blockIdx.y;
  size_t base = (size_t)bh * (2048 * 128);
  const char* gK = (const char*)(Kb + base);
  const char* gV = (const char*)(Vt + base);
  __bf16* sp = sP + w * (16 * 72);
  int b = bh >> 4, h = bh & 15;

  // ones rows (sV elements 8192..9215), never overwritten by staging
  for (int i = t; i < 1024; i += 256) sV[8192 + i] = (__bf16)1.0f;

  for (int ph = 0; ph < 2; ++ph) {
    int qt = (ph == 0) ? (int)blockIdx.x : 31 - (int)blockIdx.x;
    int q0 = qt * 64;

    bf16x8 aq[4];
    {
      const __bf16* qp = Qb + base + (size_t)(q0 + w * 16 + l16) * 128 + quad * 8;
#pragma unroll
      for (int kc = 0; kc < 4; ++kc) aq[kc] = *(const bf16x8*)(qp + kc * 32);
    }

    f32x4 o[8] = {};
    f32x4 ol = {};
    float mrow[4], alpha[4];
#pragma unroll
    for (int r = 0; r < 4; ++r) mrow[r] = -INFINITY;

    for (int kt = 0; kt <= qt; ++kt) {
      int kv0 = kt * 64;
      __syncthreads();  // LDS reuse vs previous iteration/phase
#pragma unroll
      for (int i = 0; i < 4; ++i) {
        int L = i * 256 + t;
        int row = L >> 4, sc = L & 15;
        int c = (sc & 8) | ((sc & 7) ^ (row & 7));
        gl_lds16(gK + (size_t)(kv0 + row) * 256 + c * 16, (char*)sK + L * 16);
      }
#pragma unroll
      for (int i = 0; i < 4; ++i) {
        int L = i * 256 + t;
        int row = L >> 3, sc = L & 7;
        int c = sc ^ (row & 7);
        gl_lds16(gV + (size_t)row * 4096 + kv0 * 2 + c * 16, (char*)sV + L * 16);
      }
      asm volatile("s_waitcnt vmcnt(0)" ::: "memory");
      __syncthreads();

      // S = Q K^T, pre-scaled into log2 domain
      float sv[4][4];
#pragma unroll
      for (int nt = 0; nt < 4; ++nt) {
        f32x4 z = {};
#pragma unroll
        for (int kc = 0; kc < 4; ++kc) {
          int sc = ((kc & 2) << 2) | (((((kc & 1) << 2) | quad)) ^ (l16 & 7));
          bf16x8 bk = *(const bf16x8*)(sK + (nt * 16 + l16) * 128 + sc * 8);
          z = __builtin_amdgcn_mfma_f32_16x16x32_bf16(aq[kc], bk, z, 0, 0, 0);
        }
#pragma unroll
        for (int r = 0; r < 4; ++r) sv[nt][r] = z[r] * SCL;
      }
      if (kt == qt) {  // diagonal tile: causal mask
#pragma unroll
        for (int nt = 0; nt < 4; ++nt) {
          int col = kv0 + nt * 16 + l16;
#pragma unroll
          for (int r = 0; r < 4; ++r) {
            int row = q0 + w * 16 + quad * 4 + r;
            if (col > row) sv[nt][r] = -1e9f;
          }
        }
      }
      // online softmax (max only; sum comes from the ones-column MFMA)
#pragma unroll
      for (int r = 0; r < 4; ++r) {
        float mx = fmaxf(fmaxf(sv[0][r], sv[1][r]), fmaxf(sv[2][r], sv[3][r]));
#pragma unroll
        for (int off = 1; off < 16; off <<= 1) mx = fmaxf(mx, __shfl_xor(mx, off, 64));
        float mnew = fmaxf(mrow[r], mx);
        alpha[r] = exp2f(mrow[r] - mnew);
        mrow[r] = mnew;
#pragma unroll
        for (int nt = 0; nt < 4; ++nt) sv[nt][r] = exp2f(sv[nt][r] - mnew);
      }
      // P (C-layout) -> LDS -> A-layout (wave-private region)
#pragma unroll
      for (int nt = 0; nt < 4; ++nt)
#pragma unroll
        for (int r = 0; r < 4; ++r)
          sp[(quad * 4 + r) * 72 + nt * 16 + l16] = (__bf16)sv[nt][r];
#pragma unroll
      for (int nt = 0; nt < 8; ++nt)
#pragma unroll
        for (int r = 0; r < 4; ++r) o[nt][r] *= alpha[r];
#pragma unroll
      for (int r = 0; r < 4; ++r) ol[r] *= alpha[r];
      asm volatile("s_waitcnt lgkmcnt(0)" ::: "memory");
      // O += P V ; l += P * ones
#pragma unroll
      for (int kc = 0; kc < 2; ++kc) {
        bf16x8 ap = *(const bf16x8*)(sp + l16 * 72 + kc * 32 + quad * 8);
#pragma unroll
        for (int nt = 0; nt < 8; ++nt) {
          int sc = ((kc << 2) | quad) ^ (l16 & 7);
          bf16x8 bv = *(const bf16x8*)(sV + (nt * 16 + l16) * 64 + sc * 8);
          o[nt] = __builtin_amdgcn_mfma_f32_16x16x32_bf16(ap, bv, o[nt], 0, 0, 0);
        }
        int sc = ((kc << 2) | quad) ^ (l16 & 7);
        bf16x8 bv1 = *(const bf16x8*)(sV + (128 + l16) * 64 + sc * 8);  // ones
        ol = __builtin_amdgcn_mfma_f32_16x16x32_bf16(ap, bv1, ol, 0, 0, 0);
      }
    }

    // epilogue: O/l -> attn buffer [b][s][h][d] bf16
#pragma unroll
    for (int r = 0; r < 4; ++r) {
      float inv = 1.f / ol[r];
      int srow = q0 + w * 16 + quad * 4 + r;
      __bf16* op = Ob + ((size_t)((b * 2048 + srow) * 16 + h)) * 128;
#pragma unroll
      for (int nt = 0; nt < 8; ++nt)
        op[nt * 16 + l16] = (__bf16)(o[nt][r] * inv);
    }
  }
}

extern "C" void kernel_launch(void* const* d_in, const int* in_sizes, int n_in,
                              void* d_out, int out_size, void* d_ws, size_t ws_size,
                              hipStream_t stream) {
  const float* hs   = (const float*)d_in[0];
  const float* wqkv = (const float*)d_in[2];
  const float* bqkv = (const float*)d_in[3];
  const float* wout = (const float*)d_in[4];
  const float* bout = (const float*)d_in[5];
  float* out = (float*)d_out;

  char* ws = (char*)d_ws;
  __bf16* hsb   = (__bf16*)(ws);                // [4096][2048]; reused as attnb
  __bf16* attnb = (__bf16*)(ws);
  __bf16* wqkvT = (__bf16*)(ws + 16777216);     // [6144][2048]
  __bf16* woutT = (__bf16*)(ws + 41943040);     // [2048][2048]
  __bf16* Qb    = (__bf16*)(ws + 50331648);     // [32][2048][128]
  __bf16* Kb    = (__bf16*)(ws + 67108864);     // [32][2048][128]
  __bf16* Vt    = (__bf16*)(ws + 83886080);     // [32][128][2048] (transposed V)
  // total ws use: 100,663,296 B

  k_cast<<<8192, 256, 0, stream>>>(hs, hsb, 2097152);
  k_transpose2<<<dim3(256, 64), 256, 0, stream>>>(wqkv, wqkvT, wout, woutT);
  k_gemm_qkv<<<dim3(48, 32), 256, 0, stream>>>(hsb, wqkvT, bqkv, Qb, Kb, Vt);
  k_attn<<<dim3(16, 32), 256, 0, stream>>>(Qb, Kb, Vt, attnb);
  k_gemm_out<<<dim3(16, 32), 256, 0, stream>>>(attnb, woutT, bout, out);
}

// Round 6
// 414.981 us; speedup vs baseline: 1.3666x; 1.0274x over previous
//
#include <hip/hip_runtime.h>
#include <stdint.h>
#include <math.h>

typedef float  f32x4  __attribute__((ext_vector_type(4)));
typedef __bf16 bf16x8 __attribute__((ext_vector_type(8)));
typedef __bf16 bf16x4 __attribute__((ext_vector_type(4)));

// async global->LDS, 16B per lane. LDS side must be wave-uniform base + lane*16.
__device__ __forceinline__ void gl_lds16(const void* g, void* l) {
  __builtin_amdgcn_global_load_lds(
      (__attribute__((address_space(1))) void*)(uintptr_t)g,
      (__attribute__((address_space(3))) void*)l, 16, 0, 0);
}

// ---------------- cast fp32 -> bf16, x4 vectorized ----------------
__global__ __launch_bounds__(256) void k_cast(const float* __restrict__ in,
                                              __bf16* __restrict__ out, int n4) {
  int i = blockIdx.x * 256 + threadIdx.x;
  if (i >= n4) return;
  f32x4 v = ((const f32x4*)in)[i];
  ((bf16x4*)out)[i] = __builtin_convertvector(v, bf16x4);
}

// ---------------- both weight transposes in one kernel ----------------
__global__ __launch_bounds__(256) void k_transpose2(const float* __restrict__ inA,
                                                    __bf16* __restrict__ outA,
                                                    const float* __restrict__ inB,
                                                    __bf16* __restrict__ outB) {
  __shared__ float tile[32][33];
  int bx = blockIdx.x;
  const float* in; __bf16* out; int N, n0;
  if (bx < 192) { in = inA; out = outA; N = 6144; n0 = bx * 32; }
  else          { in = inB; out = outB; N = 2048; n0 = (bx - 192) * 32; }
  const int K = 2048;
  int k0 = blockIdx.y * 32;
  int tx = threadIdx.x & 31, ty = threadIdx.x >> 5;
#pragma unroll
  for (int i = 0; i < 32; i += 8)
    tile[ty + i][tx] = in[(size_t)(k0 + ty + i) * N + n0 + tx];
  __syncthreads();
#pragma unroll
  for (int i = 0; i < 32; i += 8)
    out[(size_t)(n0 + ty + i) * K + k0 + tx] = (__bf16)tile[tx][ty + i];
}

// ---------------- QKV GEMM + fused RoPE + fused (coalesced) V-transpose ----------------
// Each 128-wide n-tile is purely Q, K, or V: which = blockIdx.x % 3, h = blockIdx.x / 3.
// V-blocks transpose the 128x128 result through LDS (two 64x132 half-tiles reusing the
// staging buffer) and store 256B-contiguous rows into Vt [bh][128][2048].
__global__ __launch_bounds__(256) void k_gemm_qkv(
    const __bf16* __restrict__ A, const __bf16* __restrict__ Bt,
    const float* __restrict__ bias,
    __bf16* __restrict__ Qo, __bf16* __restrict__ Ko, __bf16* __restrict__ Vt) {
  __shared__ __bf16 smem[2 * 128 * 64];   // sA | sB ; reused as transpose tile
  __bf16* sA = smem;
  __bf16* sB = smem + 128 * 64;
  const int K = 2048;
  int t = threadIdx.x;
  int m0 = blockIdx.y << 7, n0 = blockIdx.x << 7;
  int wave = t >> 6, lane = t & 63;
  int wr = wave >> 1, wc = wave & 1;
  int quad = lane >> 4, l16 = lane & 15, x7 = lane & 7;

  f32x4 acc[4][4] = {};

  const char* gA = (const char*)(A + (size_t)m0 * K);
  const char* gB = (const char*)(Bt + (size_t)n0 * K);

  int srcoff[4], ldsoff[4];
#pragma unroll
  for (int i = 0; i < 4; ++i) {
    int L = i * 256 + t;
    int row = L >> 3, sc = L & 7;
    int c = sc ^ (row & 7);
    srcoff[i] = row * 4096 + c * 16;
    ldsoff[i] = L * 16;
  }

  for (int k0 = 0; k0 < K; k0 += 64) {
#pragma unroll
    for (int i = 0; i < 4; ++i)
      gl_lds16(gA + (size_t)(srcoff[i] + k0 * 2), (char*)sA + ldsoff[i]);
#pragma unroll
    for (int i = 0; i < 4; ++i)
      gl_lds16(gB + (size_t)(srcoff[i] + k0 * 2), (char*)sB + ldsoff[i]);
    asm volatile("s_waitcnt vmcnt(0)" ::: "memory");
    __syncthreads();

#pragma unroll
    for (int s = 0; s < 2; ++s) {
      int slot = ((s << 2) | quad) ^ x7;
      bf16x8 af[4], bfr[4];
#pragma unroll
      for (int mt = 0; mt < 4; ++mt)
        af[mt] = *(const bf16x8*)(sA + (wr * 64 + mt * 16 + l16) * 64 + slot * 8);
#pragma unroll
      for (int nt = 0; nt < 4; ++nt)
        bfr[nt] = *(const bf16x8*)(sB + (wc * 64 + nt * 16 + l16) * 64 + slot * 8);
#pragma unroll
      for (int mt = 0; mt < 4; ++mt)
#pragma unroll
        for (int nt = 0; nt < 4; ++nt)
          acc[mt][nt] = __builtin_amdgcn_mfma_f32_16x16x32_bf16(af[mt], bfr[nt], acc[mt][nt], 0, 0, 0);
    }
    __syncthreads();
  }

  // ----- epilogue -----
  int bx = blockIdx.x;
  int h = bx / 3, which = bx - h * 3;   // n-tile is uniformly Q (0), K (1) or V (2)
  int b2 = m0 >> 11, sbase = m0 & 2047;

  if (which == 2) {
    // V: LDS transpose in two 64-d half-tiles (stride 132), coalesced store to Vt.
    for (int half = 0; half < 2; ++half) {
      if (wc == half) {
#pragma unroll
        for (int nt = 0; nt < 4; ++nt) {
          int drow = nt * 16 + l16;               // d - 64*half
          float bz = bias[n0 + half * 64 + drow];
#pragma unroll
          for (int mt = 0; mt < 4; ++mt) {
            bf16x4 v;
#pragma unroll
            for (int r = 0; r < 4; ++r) v[r] = (__bf16)(acc[mt][nt][r] + bz);
            *(bf16x4*)(smem + drow * 132 + wr * 64 + mt * 16 + quad * 4) = v;
          }
        }
      }
      __syncthreads();
      {
        int row = t >> 2, seg = t & 3;            // 4 threads per d-row, 64B each
        int d = half * 64 + row;
        __bf16* dst = Vt + ((size_t)(b2 * 16 + h) * 128 + d) * 2048 + sbase + seg * 32;
        const __bf16* src = smem + row * 132 + seg * 32;
#pragma unroll
        for (int k2 = 0; k2 < 4; ++k2)
          *(bf16x8*)(dst + k2 * 8) = *(const bf16x8*)(src + k2 * 8);
      }
      __syncthreads();
    }
  } else {
    __bf16* dst = (which == 0) ? Qo : Ko;
    float invf = exp2f(-(float)l16 * 0.83048202372184058f);  // 10000^(-l16/16)
#pragma unroll
    for (int mt = 0; mt < 4; ++mt) {
      int m = m0 + wr * 64 + mt * 16 + quad * 4;
#pragma unroll
      for (int nt = 0; nt < 4; ++nt) {
        int d = wc * 64 + nt * 16 + l16;
        float bz = bias[n0 + d];
        if (wc == 0 && nt < 2) {
          if (nt == 0) {  // RoPE pair: this lane holds d=l16 and d=l16+16
            float bz1 = bias[n0 + d + 16];
#pragma unroll
            for (int r = 0; r < 4; ++r) {
              int mm = m + r; int s = mm & 2047;
              float sn, cs;
              __sincosf((float)s * invf, &sn, &cs);
              float x1 = acc[mt][0][r] + bz;
              float x2 = acc[mt][1][r] + bz1;
              size_t off = ((size_t)(b2 * 16 + h) * 2048 + s) << 7;
              dst[off + d]      = (__bf16)(x1 * cs - x2 * sn);
              dst[off + d + 16] = (__bf16)(x2 * cs + x1 * sn);
            }
          }
        } else {
#pragma unroll
          for (int r = 0; r < 4; ++r) {
            int mm = m + r; int s = mm & 2047;
            dst[(((size_t)(b2 * 16 + h) * 2048 + s) << 7) + d] = (__bf16)(acc[mt][nt][r] + bz);
          }
        }
      }
    }
  }
}

// ---------------- Out-proj GEMM: attn[4096][2048] bf16 x Bt[2048][2048] bf16 -> f32 ----------------
__global__ __launch_bounds__(256) void k_gemm_out(
    const __bf16* __restrict__ A, const __bf16* __restrict__ Bt,
    const float* __restrict__ bias, float* __restrict__ Out) {
  __shared__ __bf16 sA[128 * 64];
  __shared__ __bf16 sB[128 * 64];
  const int K = 2048;
  int t = threadIdx.x;
  int m0 = blockIdx.y << 7, n0 = blockIdx.x << 7;
  int wave = t >> 6, lane = t & 63;
  int wr = wave >> 1, wc = wave & 1;
  int quad = lane >> 4, l16 = lane & 15, x7 = lane & 7;

  f32x4 acc[4][4] = {};

  const char* gA = (const char*)(A + (size_t)m0 * K);
  const char* gB = (const char*)(Bt + (size_t)n0 * K);

  int srcoff[4], ldsoff[4];
#pragma unroll
  for (int i = 0; i < 4; ++i) {
    int L = i * 256 + t;
    int row = L >> 3, sc = L & 7;
    int c = sc ^ (row & 7);
    srcoff[i] = row * 4096 + c * 16;
    ldsoff[i] = L * 16;
  }

  for (int k0 = 0; k0 < K; k0 += 64) {
#pragma unroll
    for (int i = 0; i < 4; ++i)
      gl_lds16(gA + (size_t)(srcoff[i] + k0 * 2), (char*)sA + ldsoff[i]);
#pragma unroll
    for (int i = 0; i < 4; ++i)
      gl_lds16(gB + (size_t)(srcoff[i] + k0 * 2), (char*)sB + ldsoff[i]);
    asm volatile("s_waitcnt vmcnt(0)" ::: "memory");
    __syncthreads();

#pragma unroll
    for (int s = 0; s < 2; ++s) {
      int slot = ((s << 2) | quad) ^ x7;
      bf16x8 af[4], bfr[4];
#pragma unroll
      for (int mt = 0; mt < 4; ++mt)
        af[mt] = *(const bf16x8*)(sA + (wr * 64 + mt * 16 + l16) * 64 + slot * 8);
#pragma unroll
      for (int nt = 0; nt < 4; ++nt)
        bfr[nt] = *(const bf16x8*)(sB + (wc * 64 + nt * 16 + l16) * 64 + slot * 8);
#pragma unroll
      for (int mt = 0; mt < 4; ++mt)
#pragma unroll
        for (int nt = 0; nt < 4; ++nt)
          acc[mt][nt] = __builtin_amdgcn_mfma_f32_16x16x32_bf16(af[mt], bfr[nt], acc[mt][nt], 0, 0, 0);
    }
    __syncthreads();
  }

#pragma unroll
  for (int mt = 0; mt < 4; ++mt) {
    int m = m0 + wr * 64 + mt * 16 + quad * 4;
#pragma unroll
    for (int nt = 0; nt < 4; ++nt) {
      int n = n0 + wc * 64 + nt * 16 + l16;
      float bz = bias[n];
#pragma unroll
      for (int r = 0; r < 4; ++r)
        Out[(size_t)(m + r) * 2048 + n] = acc[mt][nt][r] + bz;
    }
  }
}

// ---------------- causal flash attention, 128-row KV tiles ----------------
// grid (16, 32): block runs q-tiles qt=bx and 31-bx sequentially; with 128-kv
// tiles total stages/block = 17 (uniform) vs 33 before -> half the barrier drains.
// PV consumed in two 64-kv halves through wave-private sP. Row-sum l via
// ones-rows (d=128..143) appended to sV. LDS 74240 B -> 2 blocks/CU.
__global__ __launch_bounds__(256) void k_attn(const __bf16* __restrict__ Qb,
                                              const __bf16* __restrict__ Kb,
                                              const __bf16* __restrict__ Vt,
                                              __bf16* __restrict__ Ob) {
  __shared__ __bf16 sK[128 * 128];   // [kv][d], swizzled 16B chunks (16/row)
  __shared__ __bf16 sV[144 * 128];   // [d][kv], swizzled; rows 128..143 = 1.0
  __shared__ __bf16 sP[4 * 16 * 72];
  const float SCL = 0.08838834764831845f * 1.4426950408889634f;  // 1/sqrt(128)*log2e
  int t = threadIdx.x, w = t >> 6, lane = t & 63;
  int quad = lane >> 4, l16 = lane & 15;
  int bh = blockIdx.y;
  size_t base = (size_t)bh * (2048 * 128);
  const char* gK = (const char*)(Kb + base);
  const char* gV = (const char*)(Vt + base);
  __bf16* sp = sP + w * (16 * 72);
  int b = bh >> 4, h = bh & 15;

  // ones rows (sV rows 128..143), never touched by staging
  for (int i = t; i < 2048; i += 256) sV[128 * 128 + i] = (__bf16)1.0f;

  for (int ph = 0; ph < 2; ++ph) {
    int qt = (ph == 0) ? (int)blockIdx.x : 31 - (int)blockIdx.x;
    int q0 = qt * 64;
    int ntiles = (qt >> 1) + 1;

    bf16x8 aq[4];
    {
      const __bf16* qp = Qb + base + (size_t)(q0 + w * 16 + l16) * 128 + quad * 8;
#pragma unroll
      for (int kc = 0; kc < 4; ++kc) aq[kc] = *(const bf16x8*)(qp + kc * 32);
    }

    f32x4 o[8] = {};
    f32x4 ol = {};
    float mrow[4], alpha[4];
#pragma unroll
    for (int r = 0; r < 4; ++r) mrow[r] = -INFINITY;

    for (int j = 0; j < ntiles; ++j) {
      int kv0 = j << 7;
      __syncthreads();  // LDS reuse vs previous tile/phase
      // stage K tile [128 kv][128 d]: 2048 chunks, swizzled
#pragma unroll
      for (int i = 0; i < 8; ++i) {
        int L = i * 256 + t;
        int row = L >> 4, sc = L & 15;
        int c = (sc & 8) | ((sc & 7) ^ (row & 7));
        gl_lds16(gK + (size_t)(kv0 + row) * 256 + c * 16, (char*)sK + L * 16);
      }
      // stage V tile [128 d][128 kv] from Vt: 2048 chunks, swizzled
#pragma unroll
      for (int i = 0; i < 8; ++i) {
        int L = i * 256 + t;
        int row = L >> 4, sc = L & 15;
        int c = (sc & 8) | ((sc & 7) ^ (row & 7));
        gl_lds16(gV + (size_t)row * 4096 + kv0 * 2 + c * 16, (char*)sV + L * 16);
      }
      asm volatile("s_waitcnt vmcnt(0)" ::: "memory");
      __syncthreads();

      // S = Q K^T, pre-scaled into log2 domain (16 q-rows x 128 kv-cols per wave)
      float sv[8][4];
#pragma unroll
      for (int nt = 0; nt < 8; ++nt) {
        f32x4 z = {};
#pragma unroll
        for (int kc = 0; kc < 4; ++kc) {
          int sc = ((kc & 2) << 2) | (((((kc & 1) << 2) | quad)) ^ (l16 & 7));
          bf16x8 bk = *(const bf16x8*)(sK + (nt * 16 + l16) * 128 + sc * 8);
          z = __builtin_amdgcn_mfma_f32_16x16x32_bf16(aq[kc], bk, z, 0, 0, 0);
        }
#pragma unroll
        for (int r = 0; r < 4; ++r) sv[nt][r] = z[r] * SCL;
      }
      if (j == ntiles - 1) {  // tile containing the diagonal: causal mask
#pragma unroll
        for (int nt = 0; nt < 8; ++nt) {
          int col = kv0 + nt * 16 + l16;
#pragma unroll
          for (int r = 0; r < 4; ++r) {
            int row = q0 + w * 16 + quad * 4 + r;
            if (col > row) sv[nt][r] = -1e9f;
          }
        }
      }
      // online softmax (max only; sum via ones-rows MFMA)
#pragma unroll
      for (int r = 0; r < 4; ++r) {
        float mx = sv[0][r];
#pragma unroll
        for (int nt = 1; nt < 8; ++nt) mx = fmaxf(mx, sv[nt][r]);
#pragma unroll
        for (int off = 1; off < 16; off <<= 1) mx = fmaxf(mx, __shfl_xor(mx, off, 64));
        float mnew = fmaxf(mrow[r], mx);
        alpha[r] = exp2f(mrow[r] - mnew);
        mrow[r] = mnew;
#pragma unroll
        for (int nt = 0; nt < 8; ++nt) sv[nt][r] = exp2f(sv[nt][r] - mnew);
      }
      // rescale accumulators once per tile
#pragma unroll
      for (int nt = 0; nt < 8; ++nt)
#pragma unroll
        for (int r = 0; r < 4; ++r) o[nt][r] *= alpha[r];
#pragma unroll
      for (int r = 0; r < 4; ++r) ol[r] *= alpha[r];

      // PV in two 64-kv halves through wave-private sP
#pragma unroll
      for (int half = 0; half < 2; ++half) {
#pragma unroll
        for (int nt = 0; nt < 4; ++nt)
#pragma unroll
          for (int r = 0; r < 4; ++r)
            sp[(quad * 4 + r) * 72 + nt * 16 + l16] = (__bf16)sv[half * 4 + nt][r];
        asm volatile("s_waitcnt lgkmcnt(0)" ::: "memory");  // writes visible (and prior reads landed)
#pragma unroll
        for (int kc = 0; kc < 2; ++kc) {
          bf16x8 ap = *(const bf16x8*)(sp + l16 * 72 + kc * 32 + quad * 8);
          int sc = (half << 3) | (((kc << 2) | quad) ^ (l16 & 7));
#pragma unroll
          for (int nt = 0; nt < 8; ++nt) {
            bf16x8 bv = *(const bf16x8*)(sV + (nt * 16 + l16) * 128 + sc * 8);
            o[nt] = __builtin_amdgcn_mfma_f32_16x16x32_bf16(ap, bv, o[nt], 0, 0, 0);
          }
          bf16x8 bv1 = *(const bf16x8*)(sV + (128 + l16) * 128 + sc * 8);  // ones
          ol = __builtin_amdgcn_mfma_f32_16x16x32_bf16(ap, bv1, ol, 0, 0, 0);
        }
        asm volatile("s_waitcnt lgkmcnt(0)" ::: "memory");  // reads landed before sP overwrite
      }
    }

    // epilogue: O/l -> attn buffer [b][s][h][d] bf16
#pragma unroll
    for (int r = 0; r < 4; ++r) {
      float inv = 1.f / ol[r];
      int srow = q0 + w * 16 + quad * 4 + r;
      __bf16* op = Ob + ((size_t)((b * 2048 + srow) * 16 + h)) * 128;
#pragma unroll
      for (int nt = 0; nt < 8; ++nt)
        op[nt * 16 + l16] = (__bf16)(o[nt][r] * inv);
    }
  }
}

extern "C" void kernel_launch(void* const* d_in, const int* in_sizes, int n_in,
                              void* d_out, int out_size, void* d_ws, size_t ws_size,
                              hipStream_t stream) {
  const float* hs   = (const float*)d_in[0];
  const float* wqkv = (const float*)d_in[2];
  const float* bqkv = (const float*)d_in[3];
  const float* wout = (const float*)d_in[4];
  const float* bout = (const float*)d_in[5];
  float* out = (float*)d_out;

  char* ws = (char*)d_ws;
  __bf16* hsb   = (__bf16*)(ws);                // [4096][2048]; reused as attnb
  __bf16* attnb = (__bf16*)(ws);
  __bf16* wqkvT = (__bf16*)(ws + 16777216);     // [6144][2048]
  __bf16* woutT = (__bf16*)(ws + 41943040);     // [2048][2048]
  __bf16* Qb    = (__bf16*)(ws + 50331648);     // [32][2048][128]
  __bf16* Kb    = (__bf16*)(ws + 67108864);     // [32][2048][128]
  __bf16* Vt    = (__bf16*)(ws + 83886080);     // [32][128][2048] (transposed V)
  // total ws use: 100,663,296 B

  k_cast<<<8192, 256, 0, stream>>>(hs, hsb, 2097152);
  k_transpose2<<<dim3(256, 64), 256, 0, stream>>>(wqkv, wqkvT, wout, woutT);
  k_gemm_qkv<<<dim3(48, 32), 256, 0, stream>>>(hsb, wqkvT, bqkv, Qb, Kb, Vt);
  k_attn<<<dim3(16, 32), 256, 0, stream>>>(Qb, Kb, Vt, attnb);
  k_gemm_out<<<dim3(16, 32), 256, 0, stream>>>(attnb, woutT, bout, out);
}